// Round 13
// baseline (388.468 us; speedup 1.0000x reference)
//
#include <hip/hip_runtime.h>

#define N 8192
#define D 512
#define KNN 15
#define SC 8       // per-scanner register list
#define NC 16      // per-split candidate list (2 scanners merged)
#define SPLITS 8
#define NCAND 32   // rescored candidates per row
#define NPAIR 105
#define EPSF 1e-8f

#define INF __int_as_float(0x7f800000)

typedef __attribute__((ext_vector_type(4))) float f32x4;
typedef __attribute__((ext_vector_type(4))) unsigned u32x4;
typedef __attribute__((ext_vector_type(8))) short s16x8;
typedef __attribute__((ext_vector_type(8))) unsigned short u16x8;
typedef unsigned long long u64;

typedef const unsigned int __attribute__((address_space(1)))* gp_t;
typedef unsigned int __attribute__((address_space(3)))* lp_t;

__device__ __forceinline__ void gl_lds16(const void* g, void* l) {
  __builtin_amdgcn_global_load_lds((gp_t)g, (lp_t)l, 16, 0, 0);
}

__device__ __forceinline__ unsigned short bf16_rne(float x) {
  unsigned int u = __float_as_uint(x);
  return (unsigned short)((u + 0x7fffu + ((u >> 16) & 1u)) >> 16);
}

#define VMCNT4 asm volatile("s_waitcnt vmcnt(4)" ::: "memory")
#define VMCNT0 asm volatile("s_waitcnt vmcnt(0)" ::: "memory")
#define LGKM0  asm volatile("s_waitcnt lgkmcnt(0)" ::: "memory")
#define CFENCE asm volatile("" ::: "memory")

// ---------------------------------------------------------------- fused sq-norms + bf16 cast (one input pass)
__global__ __launch_bounds__(256)
void k_prep(const float* __restrict__ A, const float* __restrict__ B,
            unsigned short* __restrict__ hi, float* __restrict__ sq)
{
  const int tid = threadIdx.x;
  const int lane = tid & 63;
  const int row = blockIdx.x * 4 + (tid >> 6);    // 0 .. 2N-1
  const float* src = (row < N) ? (A + (size_t)row * D)
                               : (B + (size_t)(row - N) * D);
  const float4* s4 = (const float4*)src + lane * 2;
  const float4 x0 = s4[0], x1 = s4[1];
  const float xs[8] = {x0.x, x0.y, x0.z, x0.w, x1.x, x1.y, x1.z, x1.w};
  u16x8 hv;
  float s = 0.f;
#pragma unroll
  for (int j = 0; j < 8; ++j) {
    hv[j] = bf16_rne(xs[j]);
    s = fmaf(xs[j], xs[j], s);
  }
  *(u16x8*)(hi + (size_t)row * D + lane * 8) = hv;
#pragma unroll
  for (int o = 32; o; o >>= 1) s += __shfl_xor(s, o);
  if (lane == 0) sq[row] = s;
}

// ================================================================ stage 1 (unchanged R12 control):
// approx (hi-only) MFMA gram + per-split top-16 candidate KEYS.
__global__ __launch_bounds__(256, 4)
void k_knn1(const unsigned short* __restrict__ hi,
            const float* __restrict__ sqall,
            unsigned* __restrict__ pk)
{
  __shared__ __align__(16) char smem[40960];
  unsigned* DtU = (unsigned*)smem;          // [128][68] key tile
  unsigned* SK = (unsigned*)smem;           // [128][16] merge overlay

  const int tid = threadIdx.x;
  const int lane = tid & 63, w = tid >> 6;
  const int wr = w >> 1, wc = w & 1;
  const int fr = lane & 15, fq = lane >> 4;
  const int sgx = fq ^ ((fr >> 1) & 3);     // read-side seg swizzle

  const int rb = blockIdx.x, split = blockIdx.y, which = blockIdx.z;
  const int row0 = rb * 128;
  const int c0 = split * 1024;
  const unsigned short* Hi = hi + (size_t)which * N * D;
  const float* sq = sqall + which * N;

  const int rr = tid >> 2, sseg = tid & 3;
  const int ssg = sseg ^ ((rr >> 1) & 3);
  const unsigned short* pAh = Hi + (size_t)(row0 + rr) * D + ssg * 8;
  const unsigned short* pBh = Hi + (size_t)(c0 + rr) * D + ssg * 8;

  auto stage = [&](int sel) {
    char* d = smem + (sel << 14) + (w << 10);   // wave-uniform dest base
    gl_lds16(pAh, d);
    gl_lds16(pAh + 32768, d + 4096);            // rows +64 (+65536 B global)
    gl_lds16(pBh, d + 8192);
    gl_lds16(pBh + 32768, d + 12288);
    pAh += 32; pBh += 32;                        // next K-step
  };

  const int srow = tid >> 1, ssub = tid & 1;
  unsigned tv[SC];
#pragma unroll
  for (int j = 0; j < SC; ++j) tv[j] = 0xFFFFFFFFu;

  float sqr[4][4];
#pragma unroll
  for (int m = 0; m < 4; ++m)
#pragma unroll
    for (int j = 0; j < 4; ++j)
      sqr[m][j] = sq[row0 + wr * 64 + m * 16 + fq * 4 + j];

#pragma unroll 1
  for (int t = 0; t < 8; ++t) {
    const int ct = c0 + t * 128;
    float sqc[4];
#pragma unroll
    for (int n = 0; n < 4; ++n) sqc[n] = sq[ct + wc * 64 + n * 16 + fr];

    f32x4 acc[4][4];
#pragma unroll
    for (int m = 0; m < 4; ++m)
#pragma unroll
      for (int n = 0; n < 4; ++n) acc[m][n] = (f32x4){0.f, 0.f, 0.f, 0.f};

    stage(0);
    int cur = 0;
#pragma unroll 1
    for (int kt = 0; kt < 16; ++kt) {
      if (kt < 15) {
        stage(cur ^ 1);   // 8 outstanding
        VMCNT4;           // own 4 oldest = buf[cur] loads complete
      } else {
        VMCNT0;
      }
      __builtin_amdgcn_s_barrier();
      CFENCE;

      const short* Sb = (const short*)(smem + (cur << 14));
      s16x8 ah[4], bh[4];
#pragma unroll
      for (int m = 0; m < 4; ++m)
        ah[m] = *(const s16x8*)(Sb + (wr * 64 + m * 16 + fr) * 32 + sgx * 8);
#pragma unroll
      for (int n = 0; n < 4; ++n)
        bh[n] = *(const s16x8*)(Sb + 4096 + (wc * 64 + n * 16 + fr) * 32 + sgx * 8);
#pragma unroll
      for (int m = 0; m < 4; ++m)
#pragma unroll
        for (int n = 0; n < 4; ++n)
          acc[m][n] = __builtin_amdgcn_mfma_f32_16x16x32_bf16(ah[m], bh[n], acc[m][n], 0, 0, 0);

      LGKM0;
      __builtin_amdgcn_s_barrier();
      CFENCE;
      cur ^= 1;
    }
    pAh -= 512; pBh += 65024;

    // ---- epilogue: producer writes u32 KEYS; scanner = load + cmp + insert
#pragma unroll 1
    for (int h = 0; h < 2; ++h) {
      if (wc == h) {
#pragma unroll
        for (int m = 0; m < 4; ++m)
#pragma unroll
          for (int n = 0; n < 4; ++n) {
            const int cl = n * 16 + fr;
            const int gcol = ct + h * 64 + cl;
            const int rbase = wr * 64 + m * 16 + fq * 4;
#pragma unroll
            for (int j = 0; j < 4; ++j) {
              const float d2 = fmaf(-2.0f, acc[m][n][j], sqr[m][j] + sqc[n]);
              unsigned key = (__float_as_uint(fmaxf(d2, 0.f)) & ~8191u) | (unsigned)gcol;
              if (row0 + rbase + j == gcol) key = 0xFFFFFFFFu;   // exclude self
              DtU[(rbase + j) * 68 + cl] = key;
            }
          }
      }
      __syncthreads();
      {
        unsigned kth = tv[SC - 1];
#pragma unroll 1
        for (int g = 0; g < 8; ++g) {
          const u32x4 dv = *(const u32x4*)&DtU[srow * 68 + ssub * 32 + g * 4];
#pragma unroll
          for (int i = 0; i < 4; ++i) {
            unsigned key = dv[i];
            if (key < kth) {
#pragma unroll
              for (int j = 0; j < SC; ++j) {
                const unsigned lo = min(tv[j], key);
                key = max(tv[j], key);
                tv[j] = lo;
              }
              kth = tv[SC - 1];
            }
          }
        }
      }
      __syncthreads();
    }
  }

  // ---- block end: merge 2 sorted scanner lists per row -> sorted top-16 keys
#pragma unroll
  for (int j = 0; j < SC; ++j) SK[srow * 16 + ssub * 8 + j] = tv[j];
  __syncthreads();
  if (tid < 128) {
    const int grow = row0 + tid;
    const size_t pb = (((size_t)which * SPLITS + split) * N + grow) * NC;
    int p0 = 0, p1 = 0;
#pragma unroll
    for (int j = 0; j < NC; ++j) {
      const unsigned a = (p0 < SC) ? SK[tid * 16 + p0] : 0xFFFFFFFFu;
      const unsigned b = (p1 < SC) ? SK[tid * 16 + 8 + p1] : 0xFFFFFFFFu;
      const bool ta = a <= b;
      pk[pb + j] = ta ? a : b;
      if (ta) ++p0; else ++p1;
    }
  }
}

// ================================================================ fused tail, 4-wave:
// Phase A: waves 0/1 bitonic-128 key merge -> cand idx in LDS; ALL 4 waves
// rescore (16 dots each, wave pairs {0,2}=ref {1,3}=cur); waves 0/1 final
// bitonic-64 -> top-15. Phase B: ref/cur grams CONCURRENT (2 waves each).
__global__ __launch_bounds__(256)
void k_tail(const float* __restrict__ emb, const float* __restrict__ ref,
            const float* __restrict__ sqall, const unsigned* __restrict__ pk,
            float* __restrict__ dens, float* __restrict__ l1p,
            float* __restrict__ angp)
{
  __shared__ __align__(16) short Vb[2][16][520];   // 33280 B
  __shared__ float Gp[4][256];
  __shared__ float G2[2][256];
  __shared__ float invn[2][16];
  __shared__ int cand[2][32];
  __shared__ u64 kbuf[2][32];
  __shared__ int idxs[2][16];      // [0]=ref neighbors, [1]=cur
  __shared__ float dls[2][16];
  __shared__ float red2[256];

  const int i = blockIdx.x;
  const int tid = threadIdx.x;
  const int lane = tid & 63;
  const int w = tid >> 6;

  // ---- Phase A0: waves 0/1 sort the 128 candidate keys (slot 0=ref, 1=cur)
  if (w < 2) {
    const int which = 1 - w;                 // slot w: 0->ref(which=1), 1->cur
    const int sp = lane >> 3, jj = lane & 7;
    const size_t kb = (((size_t)which * SPLITS + sp) * N + i) * NC;
    unsigned v0 = pk[kb + jj];
    unsigned v1 = pk[kb + 8 + jj];
#pragma unroll
    for (int k = 2; k <= 128; k <<= 1) {
#pragma unroll
      for (int s = k >> 1; s > 0; s >>= 1) {
        if (s == 64) {
          const unsigned mn = min(v0, v1), mx = max(v0, v1);
          v0 = mn; v1 = mx;
        } else {
          const unsigned o0 = __shfl_xor(v0, s);
          const unsigned o1 = __shfl_xor(v1, s);
          const bool low = ((lane & s) == 0);
          const bool dir0 = ((lane & k) == 0);
          const bool dir1 = (((64 + lane) & k) == 0);
          const unsigned a0 = min(v0, o0), b0 = max(v0, o0);
          v0 = (low == dir0) ? a0 : b0;
          const unsigned a1 = min(v1, o1), b1 = max(v1, o1);
          v1 = (low == dir1) ? a1 : b1;
        }
      }
    }
    if (lane < NCAND) cand[w][lane] = (int)(v0 & 8191u);
  }
  __syncthreads();

  // ---- Phase A1: all 4 waves compute exact dots (16 each)
  {
    const int slot = w & 1, half = w >> 1;
    const int which = 1 - slot;
    const float* E = which ? ref : emb;
    const float* sqm = sqall + which * N;

    const float4* orow = (const float4*)(E + (size_t)i * D) + lane * 2;
    const float4 o0 = orow[0], o1 = orow[1];
    const float sqr_ = sqm[i];

    u64 myk = ~0ull;
#pragma unroll 4
    for (int c = 0; c < 16; ++c) {
      const int cl = cand[slot][half * 16 + c];    // uniform -> broadcast
      const float4* crow = (const float4*)(E + (size_t)cl * D) + lane * 2;
      const float4 c0 = crow[0], c1 = crow[1];
      float s = o0.x*c0.x + o0.y*c0.y + o0.z*c0.z + o0.w*c0.w
              + o1.x*c1.x + o1.y*c1.y + o1.z*c1.z + o1.w*c1.w;
#pragma unroll
      for (int o = 32; o; o >>= 1) s += __shfl_xor(s, o);
      float d2 = fmaf(-2.0f, s, sqr_ + sqm[cl]);
      d2 = fmaxf(d2, 0.0f);
      const u64 key = ((u64)__float_as_uint(d2) << 32) | (unsigned)cl;
      if (lane == c) myk = key;
    }
    if (lane < 16) kbuf[slot][half * 16 + lane] = myk;
  }
  __syncthreads();

  // ---- Phase A2: waves 0/1 sort 32 exact keys -> top-15
  if (w < 2) {
    u64 mykey = (lane < NCAND) ? kbuf[w][lane] : ~0ull;
#pragma unroll
    for (int k = 2; k <= 64; k <<= 1) {
#pragma unroll
      for (int j = k >> 1; j > 0; j >>= 1) {
        const u64 o = __shfl_xor(mykey, j);
        const bool up = ((lane & k) == 0);
        const bool lower = ((lane & j) == 0);
        const u64 mn = (mykey < o) ? mykey : o;
        const u64 mx = (mykey < o) ? o : mykey;
        mykey = (lower == up) ? mn : mx;
      }
    }
    if (lane < KNN) {
      const float d2v = __uint_as_float((unsigned)(mykey >> 32));
      dls[w][lane] = (d2v > 0.f) ? sqrtf(fmaxf(d2v, 1e-24f)) : 0.f;
      idxs[w][lane] = (int)(mykey & 0xffffffffu);
    }
  }
  __syncthreads();

  // ---- Phase A3: per-point stats (dls[0]=ref, dls[1]=cur)
  if (tid == 0) {
    float mr = 0.f, mc = 0.f;
#pragma unroll
    for (int j = 0; j < KNN; ++j) { mr += dls[0][j]; mc += dls[1][j]; }
    mr *= (1.0f / KNN); mc *= (1.0f / KNN);
    const float ir = 1.0f / (mr + EPSF);
    const float ic = 1.0f / (mc + EPSF);
    float s1 = 0.f;
#pragma unroll
    for (int j = 0; j < KNN; ++j) {
      const float t = dls[1][j] * ic - dls[0][j] * ir;
      s1 = fmaf(t, t, s1);
    }
    dens[i] = ic;
    dens[N + i] = ir;
    l1p[i] = s1;
  }

  // ---- Phase B: both grams concurrent. waves 0,1 -> pass 0 (ref, idxs[0]);
  //      waves 2,3 -> pass 1 (cur, idxs[1]). w2 = wave-in-pass.
  {
    const int p = w >> 1, w2 = w & 1;
    const float* E = p ? emb : ref;
    const int base = lane * 8;

    const float4* er = (const float4*)(E + (size_t)i * D) + lane * 2;
    const float4 e0 = er[0], e1 = er[1];

#pragma unroll 1
    for (int j = w2; j < 16; j += 2) {
      u16x8 hv;
      if (j < 15) {
        const float* src = E + (size_t)idxs[p][j] * D;
        const float4 x0 = *(const float4*)(src + base);
        const float4 x1 = *(const float4*)(src + base + 4);
        const float dd[8] = {x0.x-e0.x, x0.y-e0.y, x0.z-e0.z, x0.w-e0.w,
                             x1.x-e1.x, x1.y-e1.y, x1.z-e1.z, x1.w-e1.w};
#pragma unroll
        for (int q = 0; q < 8; ++q) hv[q] = bf16_rne(dd[q]);
      } else {
#pragma unroll
        for (int q = 0; q < 8; ++q) hv[q] = 0;
      }
      *(u16x8*)&Vb[p][j][base] = hv;
    }
  }
  __syncthreads();

  {
    const int p = w >> 1, w2 = w & 1;
    const int r = lane & 15, fq = lane >> 4;
    f32x4 g = (f32x4){0.f, 0.f, 0.f, 0.f};
#pragma unroll
    for (int s = 0; s < 8; ++s) {
      const s16x8 f = *(const s16x8*)&Vb[p][r][w2 * 256 + s * 32 + fq * 8];
      g = __builtin_amdgcn_mfma_f32_16x16x32_bf16(f, f, g, 0, 0, 0);
    }
#pragma unroll
    for (int r2 = 0; r2 < 4; ++r2)
      Gp[w][(fq * 4 + r2) * 16 + r] = g[r2];
  }
  __syncthreads();

  G2[0][tid] = Gp[0][tid] + Gp[1][tid];
  G2[1][tid] = Gp[2][tid] + Gp[3][tid];
  __syncthreads();
  if (tid < 32) {
    const int p = tid >> 4, r = tid & 15;
    invn[p][r] = 1.0f / fmaxf(sqrtf(G2[p][r * 17]), 1e-12f);
  }
  __syncthreads();

  float acc = 0.f;
  if (tid < NPAIR) {
    int a = 0, q = tid, rem = KNN - 1;
    while (q >= rem) { q -= rem; ++a; --rem; }
    const int b = a + 1 + q;
    const float cos0 = G2[0][a * 16 + b] * invn[0][a] * invn[0][b];
    const float cos1 = G2[1][a * 16 + b] * invn[1][a] * invn[1][b];
    const float dd = cos1 - cos0;
    acc = dd * dd;
  }

  red2[tid] = acc;
  __syncthreads();
  for (int o = 128; o; o >>= 1) {
    if (tid < o) red2[tid] += red2[tid + o];
    __syncthreads();
  }
  if (tid == 0) angp[i] = red2[0];
}

// ---------------------------------------------------------------- final combine
__global__ __launch_bounds__(256)
void k_final(const float* __restrict__ l1p, const float* __restrict__ dens,
             const float* __restrict__ angp, float* __restrict__ out)
{
  __shared__ float red[256];
  const int t = threadIdx.x;

  float sc = 0.f, sr = 0.f;
  for (int n = t; n < N; n += 256) { sc += dens[n]; sr += dens[N + n]; }
  red[t] = sc; __syncthreads();
  for (int o = 128; o; o >>= 1) { if (t < o) red[t] += red[t + o]; __syncthreads(); }
  float scm = red[0]; __syncthreads();
  red[t] = sr; __syncthreads();
  for (int o = 128; o; o >>= 1) { if (t < o) red[t] += red[t + o]; __syncthreads(); }
  float srm = red[0]; __syncthreads();

  const float icm = 1.0f / (scm / (float)N + EPSF);
  const float irm = 1.0f / (srm / (float)N + EPSF);

  float l2 = 0.f;
  for (int n = t; n < N; n += 256) {
    const float dd = dens[n] * icm - dens[N + n] * irm;
    l2 = fmaf(dd, dd, l2);
  }
  red[t] = l2; __syncthreads();
  for (int o = 128; o; o >>= 1) { if (t < o) red[t] += red[t + o]; __syncthreads(); }
  const float l2sum = red[0]; __syncthreads();

  float l1 = 0.f;
  for (int n = t; n < N; n += 256) l1 += l1p[n];
  red[t] = l1; __syncthreads();
  for (int o = 128; o; o >>= 1) { if (t < o) red[t] += red[t + o]; __syncthreads(); }
  const float l1sum = red[0]; __syncthreads();

  float l3 = 0.f;
  for (int n = t; n < N; n += 256) l3 += angp[n];
  red[t] = l3; __syncthreads();
  for (int o = 128; o; o >>= 1) { if (t < o) red[t] += red[t + o]; __syncthreads(); }
  const float l3sum = red[0];

  if (t == 0) {
    out[0] = l1sum / (float)(N * KNN)
           + 0.5f * l2sum / (float)N
           + 0.5f * l3sum / (float)(N * NPAIR);
  }
}

// ---------------------------------------------------------------- launch
extern "C" void kernel_launch(void* const* d_in, const int* in_sizes, int n_in,
                              void* d_out, int out_size, void* d_ws, size_t ws_size,
                              hipStream_t stream)
{
  const float* emb = (const float*)d_in[0];
  const float* ref = (const float*)d_in[1];
  float* out = (float*)d_out;
  char* ws = (char*)d_ws;

  const size_t off_sq   = 0;                                            // 2N f32
  const size_t off_hi   = off_sq + (size_t)2 * N * 4;                   // 2ND bf16
  const size_t off_pk   = off_hi + (size_t)2 * N * D * 2;               // 2*8*N*16 u32
  const size_t off_dens = off_pk + (size_t)2 * SPLITS * N * NC * 4;     // 2N f32
  const size_t off_l1   = off_dens + (size_t)2 * N * 4;                 // N f32
  const size_t off_ang  = off_l1 + (size_t)N * 4;                       // N f32

  float* sq = (float*)(ws + off_sq);
  unsigned short* hi = (unsigned short*)(ws + off_hi);
  unsigned* pk = (unsigned*)(ws + off_pk);
  float* dens = (float*)(ws + off_dens);
  float* l1p = (float*)(ws + off_l1);
  float* angp = (float*)(ws + off_ang);

  k_prep<<<(2 * N) / 4, 256, 0, stream>>>(emb, ref, hi, sq);
  k_knn1<<<dim3(N / 128, SPLITS, 2), 256, 0, stream>>>(hi, sq, pk);
  k_tail<<<N, 256, 0, stream>>>(emb, ref, sq, pk, dens, l1p, angp);
  k_final<<<1, 256, 0, stream>>>(l1p, dens, angp, out);
}

// Round 14
// 358.652 us; speedup vs baseline: 1.0831x; 1.0831x over previous
//
#include <hip/hip_runtime.h>

#define N 8192
#define D 512
#define KNN 15
#define SC 8       // per-scanner register list
#define NC 16      // per-split candidate list (2 scanners merged)
#define SPLITS 8
#define NCAND 32   // rescored candidates per row
#define NPAIR 105
#define EPSF 1e-8f

#define INF __int_as_float(0x7f800000)

typedef __attribute__((ext_vector_type(4))) float f32x4;
typedef __attribute__((ext_vector_type(4))) unsigned u32x4;
typedef __attribute__((ext_vector_type(8))) short s16x8;
typedef __attribute__((ext_vector_type(8))) unsigned short u16x8;
typedef unsigned long long u64;

typedef const unsigned int __attribute__((address_space(1)))* gp_t;
typedef unsigned int __attribute__((address_space(3)))* lp_t;

__device__ __forceinline__ void gl_lds16(const void* g, void* l) {
  __builtin_amdgcn_global_load_lds((gp_t)g, (lp_t)l, 16, 0, 0);
}

__device__ __forceinline__ unsigned short bf16_rne(float x) {
  unsigned int u = __float_as_uint(x);
  return (unsigned short)((u + 0x7fffu + ((u >> 16) & 1u)) >> 16);
}

#define VMCNT4 asm volatile("s_waitcnt vmcnt(4)" ::: "memory")
#define VMCNT0 asm volatile("s_waitcnt vmcnt(0)" ::: "memory")
#define LGKM0  asm volatile("s_waitcnt lgkmcnt(0)" ::: "memory")
#define CFENCE asm volatile("" ::: "memory")

// ---------------------------------------------------------------- fused sq-norms + bf16 cast (one input pass)
__global__ __launch_bounds__(256)
void k_prep(const float* __restrict__ A, const float* __restrict__ B,
            unsigned short* __restrict__ hi, float* __restrict__ sq)
{
  const int tid = threadIdx.x;
  const int lane = tid & 63;
  const int row = blockIdx.x * 4 + (tid >> 6);    // 0 .. 2N-1
  const float* src = (row < N) ? (A + (size_t)row * D)
                               : (B + (size_t)(row - N) * D);
  const float4* s4 = (const float4*)src + lane * 2;
  const float4 x0 = s4[0], x1 = s4[1];
  const float xs[8] = {x0.x, x0.y, x0.z, x0.w, x1.x, x1.y, x1.z, x1.w};
  u16x8 hv;
  float s = 0.f;
#pragma unroll
  for (int j = 0; j < 8; ++j) {
    hv[j] = bf16_rne(xs[j]);
    s = fmaf(xs[j], xs[j], s);
  }
  *(u16x8*)(hi + (size_t)row * D + lane * 8) = hv;
#pragma unroll
  for (int o = 32; o; o >>= 1) s += __shfl_xor(s, o);
  if (lane == 0) sq[row] = s;
}

// ================================================================ stage 1:
// approx (hi-only) MFMA gram + per-split top-16 candidate KEYS.
// key u32 = (f32bits(max(d2,0)) & ~8191) | global_col  (col < 8192, 13 bits).
// Scanner insert uses the dependency-free sorted-insert network
// (tv'[j] = min(tv[j], max(tv[j-1], key))) — identical result, depth 2.
__global__ __launch_bounds__(256, 4)
void k_knn1(const unsigned short* __restrict__ hi,
            const float* __restrict__ sqall,
            unsigned* __restrict__ pk)
{
  __shared__ __align__(16) char smem[40960];
  unsigned* DtU = (unsigned*)smem;          // [128][68] key tile
  unsigned* SK = (unsigned*)smem;           // [128][16] merge overlay

  const int tid = threadIdx.x;
  const int lane = tid & 63, w = tid >> 6;
  const int wr = w >> 1, wc = w & 1;
  const int fr = lane & 15, fq = lane >> 4;
  const int sgx = fq ^ ((fr >> 1) & 3);     // read-side seg swizzle

  const int rb = blockIdx.x, split = blockIdx.y, which = blockIdx.z;
  const int row0 = rb * 128;
  const int c0 = split * 1024;
  const unsigned short* Hi = hi + (size_t)which * N * D;
  const float* sq = sqall + which * N;

  const int rr = tid >> 2, sseg = tid & 3;
  const int ssg = sseg ^ ((rr >> 1) & 3);
  const unsigned short* pAh = Hi + (size_t)(row0 + rr) * D + ssg * 8;
  const unsigned short* pBh = Hi + (size_t)(c0 + rr) * D + ssg * 8;

  auto stage = [&](int sel) {
    char* d = smem + (sel << 14) + (w << 10);   // wave-uniform dest base
    gl_lds16(pAh, d);
    gl_lds16(pAh + 32768, d + 4096);            // rows +64 (+65536 B global)
    gl_lds16(pBh, d + 8192);
    gl_lds16(pBh + 32768, d + 12288);
    pAh += 32; pBh += 32;                        // next K-step
  };

  const int srow = tid >> 1, ssub = tid & 1;
  unsigned tv[SC];
#pragma unroll
  for (int j = 0; j < SC; ++j) tv[j] = 0xFFFFFFFFu;

  float sqr[4][4];
#pragma unroll
  for (int m = 0; m < 4; ++m)
#pragma unroll
    for (int j = 0; j < 4; ++j)
      sqr[m][j] = sq[row0 + wr * 64 + m * 16 + fq * 4 + j];

#pragma unroll 1
  for (int t = 0; t < 8; ++t) {
    const int ct = c0 + t * 128;
    float sqc[4];
#pragma unroll
    for (int n = 0; n < 4; ++n) sqc[n] = sq[ct + wc * 64 + n * 16 + fr];

    f32x4 acc[4][4];
#pragma unroll
    for (int m = 0; m < 4; ++m)
#pragma unroll
      for (int n = 0; n < 4; ++n) acc[m][n] = (f32x4){0.f, 0.f, 0.f, 0.f};

    stage(0);
    int cur = 0;
#pragma unroll 1
    for (int kt = 0; kt < 16; ++kt) {
      if (kt < 15) {
        stage(cur ^ 1);   // 8 outstanding
        VMCNT4;           // own 4 oldest = buf[cur] loads complete
      } else {
        VMCNT0;
      }
      __builtin_amdgcn_s_barrier();
      CFENCE;

      const short* Sb = (const short*)(smem + (cur << 14));
      s16x8 ah[4], bh[4];
#pragma unroll
      for (int m = 0; m < 4; ++m)
        ah[m] = *(const s16x8*)(Sb + (wr * 64 + m * 16 + fr) * 32 + sgx * 8);
#pragma unroll
      for (int n = 0; n < 4; ++n)
        bh[n] = *(const s16x8*)(Sb + 4096 + (wc * 64 + n * 16 + fr) * 32 + sgx * 8);
#pragma unroll
      for (int m = 0; m < 4; ++m)
#pragma unroll
        for (int n = 0; n < 4; ++n)
          acc[m][n] = __builtin_amdgcn_mfma_f32_16x16x32_bf16(ah[m], bh[n], acc[m][n], 0, 0, 0);

      LGKM0;
      __builtin_amdgcn_s_barrier();
      CFENCE;
      cur ^= 1;
    }
    pAh -= 512; pBh += 65024;

    // ---- epilogue: producer writes u32 KEYS; scanner = load + cmp + insert
#pragma unroll 1
    for (int h = 0; h < 2; ++h) {
      if (wc == h) {
#pragma unroll
        for (int m = 0; m < 4; ++m)
#pragma unroll
          for (int n = 0; n < 4; ++n) {
            const int cl = n * 16 + fr;
            const int gcol = ct + h * 64 + cl;
            const int rbase = wr * 64 + m * 16 + fq * 4;
#pragma unroll
            for (int j = 0; j < 4; ++j) {
              const float d2 = fmaf(-2.0f, acc[m][n][j], sqr[m][j] + sqc[n]);
              unsigned key = (__float_as_uint(fmaxf(d2, 0.f)) & ~8191u) | (unsigned)gcol;
              if (row0 + rbase + j == gcol) key = 0xFFFFFFFFu;   // exclude self
              DtU[(rbase + j) * 68 + cl] = key;
            }
          }
      }
      __syncthreads();
      {
        unsigned kth = tv[SC - 1];
#pragma unroll 1
        for (int g = 0; g < 8; ++g) {
          const u32x4 dv = *(const u32x4*)&DtU[srow * 68 + ssub * 32 + g * 4];
#pragma unroll
          for (int i = 0; i < 4; ++i) {
            const unsigned key = dv[i];
            if (key < kth) {
              // parallel sorted-insert: all slots read OLD tv, no serial chain
#pragma unroll
              for (int j = SC - 1; j >= 1; --j)
                tv[j] = min(tv[j], max(tv[j - 1], key));
              tv[0] = min(tv[0], key);
              kth = tv[SC - 1];
            }
          }
        }
      }
      __syncthreads();
    }
  }

  // ---- block end: merge 2 sorted scanner lists per row -> sorted top-16 keys
#pragma unroll
  for (int j = 0; j < SC; ++j) SK[srow * 16 + ssub * 8 + j] = tv[j];
  __syncthreads();
  if (tid < 128) {
    const int grow = row0 + tid;
    const size_t pb = (((size_t)which * SPLITS + split) * N + grow) * NC;
    int p0 = 0, p1 = 0;
#pragma unroll
    for (int j = 0; j < NC; ++j) {
      const unsigned a = (p0 < SC) ? SK[tid * 16 + p0] : 0xFFFFFFFFu;
      const unsigned b = (p1 < SC) ? SK[tid * 16 + 8 + p1] : 0xFFFFFFFFu;
      const bool ta = a <= b;
      pk[pb + j] = ta ? a : b;
      if (ta) ++p0; else ++p1;
    }
  }
}

// ================================================================ fused tail (R12 proven version):
// per point i: rescore ref (wave 0) + cur (wave 1) via bitonic-128 candidate
// merge -> exact f32 top-15; in-LDS handoff; per-point stats; MFMA angular.
__global__ __launch_bounds__(256)
void k_tail(const float* __restrict__ emb, const float* __restrict__ ref,
            const float* __restrict__ sqall, const unsigned* __restrict__ pk,
            float* __restrict__ dens, float* __restrict__ l1p,
            float* __restrict__ angp)
{
  __shared__ __align__(16) short Vb[16][520];
  __shared__ float Gp[4][256];
  __shared__ float G[256];
  __shared__ float invn[16];
  __shared__ float cref[NPAIR];
  __shared__ float red2[256];
  __shared__ int idxs[2][16];      // [0]=ref neighbors, [1]=cur
  __shared__ float dls[2][16];

  const int i = blockIdx.x;
  const int tid = threadIdx.x;
  const int lane = tid & 63;
  const int w = tid >> 6;

  // ---- Phase A: waves 0 (ref, which=1) and 1 (cur, which=0) rescore
  if (w < 2) {
    const int which = 1 - w;
    const float* E = which ? ref : emb;
    const float* sqm = sqall + which * N;

    // load 128 candidate keys (8 splits x 16), 2 per lane
    const int sp = lane >> 3, jj = lane & 7;
    const size_t kb = (((size_t)which * SPLITS + sp) * N + i) * NC;
    unsigned v0 = pk[kb + jj];
    unsigned v1 = pk[kb + 8 + jj];

    // bitonic sort 128 ascending; element g: g<64 -> v0[lane g], g>=64 -> v1[lane g-64]
#pragma unroll
    for (int k = 2; k <= 128; k <<= 1) {
#pragma unroll
      for (int s = k >> 1; s > 0; s >>= 1) {
        if (s == 64) {                       // only at k=128; pair (v0,v1), ascending
          const unsigned mn = min(v0, v1), mx = max(v0, v1);
          v0 = mn; v1 = mx;
        } else {
          const unsigned o0 = __shfl_xor(v0, s);
          const unsigned o1 = __shfl_xor(v1, s);
          const bool low = ((lane & s) == 0);
          const bool dir0 = ((lane & k) == 0);          // g = lane
          const bool dir1 = (((64 + lane) & k) == 0);   // g = 64+lane
          const unsigned a0 = min(v0, o0), b0 = max(v0, o0);
          v0 = (low == dir0) ? a0 : b0;
          const unsigned a1 = min(v1, o1), b1 = max(v1, o1);
          v1 = (low == dir1) ? a1 : b1;
        }
      }
    }
    // candidates = 32 smallest = v0 of lanes 0..31

    const float4* orow = (const float4*)(E + (size_t)i * D) + lane * 2;
    const float4 o0 = orow[0], o1 = orow[1];
    const float sqr_ = sqm[i];

    u64 mykey = ~0ull;
#pragma unroll 4
    for (int c = 0; c < NCAND; ++c) {
      const int cl = (int)(__shfl(v0, c) & 8191u);
      const float4* crow = (const float4*)(E + (size_t)cl * D) + lane * 2;
      const float4 c0 = crow[0], c1 = crow[1];
      float s = o0.x*c0.x + o0.y*c0.y + o0.z*c0.z + o0.w*c0.w
              + o1.x*c1.x + o1.y*c1.y + o1.z*c1.z + o1.w*c1.w;
#pragma unroll
      for (int o = 32; o; o >>= 1) s += __shfl_xor(s, o);
      float d2 = fmaf(-2.0f, s, sqr_ + sqm[cl]);
      d2 = fmaxf(d2, 0.0f);
      const u64 key = ((u64)__float_as_uint(d2) << 32) | (unsigned)cl;
      if (lane == c) mykey = key;
    }

    // bitonic sort ascending across 64 lanes (lanes >= NCAND hold ~0ull)
#pragma unroll
    for (int k = 2; k <= 64; k <<= 1) {
#pragma unroll
      for (int j = k >> 1; j > 0; j >>= 1) {
        const u64 o = __shfl_xor(mykey, j);
        const bool up = ((lane & k) == 0);
        const bool lower = ((lane & j) == 0);
        const u64 mn = (mykey < o) ? mykey : o;
        const u64 mx = (mykey < o) ? o : mykey;
        mykey = (lower == up) ? mn : mx;
      }
    }

    if (lane < KNN) {
      const float d2v = __uint_as_float((unsigned)(mykey >> 32));
      dls[w][lane] = (d2v > 0.f) ? sqrtf(fmaxf(d2v, 1e-24f)) : 0.f;
      idxs[w][lane] = (int)(mykey & 0xffffffffu);
    }
  }
  __syncthreads();

  // ---- Phase A2: per-point stats (dls[0]=ref, dls[1]=cur)
  if (tid == 0) {
    float mr = 0.f, mc = 0.f;
#pragma unroll
    for (int j = 0; j < KNN; ++j) { mr += dls[0][j]; mc += dls[1][j]; }
    mr *= (1.0f / KNN); mc *= (1.0f / KNN);
    const float ir = 1.0f / (mr + EPSF);
    const float ic = 1.0f / (mc + EPSF);
    float s1 = 0.f;
#pragma unroll
    for (int j = 0; j < KNN; ++j) {
      const float t = dls[1][j] * ic - dls[0][j] * ir;
      s1 = fmaf(t, t, s1);
    }
    dens[i] = ic;
    dens[N + i] = ir;
    l1p[i] = s1;
  }
  __syncthreads();

  // ---- Phase B: angular via per-point MFMA gram (pass 0 = ref, 1 = cur)
  const int base = lane * 8;
  float acc = 0.f;

#pragma unroll 1
  for (int pass = 0; pass < 2; ++pass) {
    const float* E = pass ? emb : ref;

    const float4* er = (const float4*)(E + (size_t)i * D) + lane * 2;
    const float4 e0 = er[0], e1 = er[1];

#pragma unroll 1
    for (int j = w; j < 16; j += 4) {
      u16x8 hv;
      if (j < 15) {
        const float* src = E + (size_t)idxs[pass][j] * D;
        const float4 x0 = *(const float4*)(src + base);
        const float4 x1 = *(const float4*)(src + base + 4);
        const float dd[8] = {x0.x-e0.x, x0.y-e0.y, x0.z-e0.z, x0.w-e0.w,
                             x1.x-e1.x, x1.y-e1.y, x1.z-e1.z, x1.w-e1.w};
#pragma unroll
        for (int q = 0; q < 8; ++q) hv[q] = bf16_rne(dd[q]);
      } else {
#pragma unroll
        for (int q = 0; q < 8; ++q) hv[q] = 0;
      }
      *(u16x8*)&Vb[j][base] = hv;
    }
    __syncthreads();

    {
      const int r = lane & 15, fq = lane >> 4;
      f32x4 g = (f32x4){0.f, 0.f, 0.f, 0.f};
#pragma unroll
      for (int s = 0; s < 4; ++s) {
        const s16x8 f = *(const s16x8*)&Vb[r][w * 128 + s * 32 + fq * 8];
        g = __builtin_amdgcn_mfma_f32_16x16x32_bf16(f, f, g, 0, 0, 0);
      }
#pragma unroll
      for (int r2 = 0; r2 < 4; ++r2)
        Gp[w][(fq * 4 + r2) * 16 + r] = g[r2];
    }
    __syncthreads();

    G[tid] = Gp[0][tid] + Gp[1][tid] + Gp[2][tid] + Gp[3][tid];
    __syncthreads();
    if (tid < 16) invn[tid] = 1.0f / fmaxf(sqrtf(G[tid * 17]), 1e-12f);
    __syncthreads();

    if (tid < NPAIR) {
      int a = 0, q = tid, rem = KNN - 1;
      while (q >= rem) { q -= rem; ++a; --rem; }
      const int b = a + 1 + q;
      const float cosv = G[a * 16 + b] * invn[a] * invn[b];
      if (pass == 0) cref[tid] = cosv;
      else { const float dd = cosv - cref[tid]; acc = dd * dd; }
    }
    __syncthreads();
  }

  red2[tid] = acc;
  __syncthreads();
  for (int o = 128; o; o >>= 1) {
    if (tid < o) red2[tid] += red2[tid + o];
    __syncthreads();
  }
  if (tid == 0) angp[i] = red2[0];
}

// ---------------------------------------------------------------- final combine
__global__ __launch_bounds__(256)
void k_final(const float* __restrict__ l1p, const float* __restrict__ dens,
             const float* __restrict__ angp, float* __restrict__ out)
{
  __shared__ float red[256];
  const int t = threadIdx.x;

  float sc = 0.f, sr = 0.f;
  for (int n = t; n < N; n += 256) { sc += dens[n]; sr += dens[N + n]; }
  red[t] = sc; __syncthreads();
  for (int o = 128; o; o >>= 1) { if (t < o) red[t] += red[t + o]; __syncthreads(); }
  float scm = red[0]; __syncthreads();
  red[t] = sr; __syncthreads();
  for (int o = 128; o; o >>= 1) { if (t < o) red[t] += red[t + o]; __syncthreads(); }
  float srm = red[0]; __syncthreads();

  const float icm = 1.0f / (scm / (float)N + EPSF);
  const float irm = 1.0f / (srm / (float)N + EPSF);

  float l2 = 0.f;
  for (int n = t; n < N; n += 256) {
    const float dd = dens[n] * icm - dens[N + n] * irm;
    l2 = fmaf(dd, dd, l2);
  }
  red[t] = l2; __syncthreads();
  for (int o = 128; o; o >>= 1) { if (t < o) red[t] += red[t + o]; __syncthreads(); }
  const float l2sum = red[0]; __syncthreads();

  float l1 = 0.f;
  for (int n = t; n < N; n += 256) l1 += l1p[n];
  red[t] = l1; __syncthreads();
  for (int o = 128; o; o >>= 1) { if (t < o) red[t] += red[t + o]; __syncthreads(); }
  const float l1sum = red[0]; __syncthreads();

  float l3 = 0.f;
  for (int n = t; n < N; n += 256) l3 += angp[n];
  red[t] = l3; __syncthreads();
  for (int o = 128; o; o >>= 1) { if (t < o) red[t] += red[t + o]; __syncthreads(); }
  const float l3sum = red[0];

  if (t == 0) {
    out[0] = l1sum / (float)(N * KNN)
           + 0.5f * l2sum / (float)N
           + 0.5f * l3sum / (float)(N * NPAIR);
  }
}

// ---------------------------------------------------------------- launch
extern "C" void kernel_launch(void* const* d_in, const int* in_sizes, int n_in,
                              void* d_out, int out_size, void* d_ws, size_t ws_size,
                              hipStream_t stream)
{
  const float* emb = (const float*)d_in[0];
  const float* ref = (const float*)d_in[1];
  float* out = (float*)d_out;
  char* ws = (char*)d_ws;

  const size_t off_sq   = 0;                                            // 2N f32
  const size_t off_hi   = off_sq + (size_t)2 * N * 4;                   // 2ND bf16
  const size_t off_pk   = off_hi + (size_t)2 * N * D * 2;               // 2*8*N*16 u32
  const size_t off_dens = off_pk + (size_t)2 * SPLITS * N * NC * 4;     // 2N f32
  const size_t off_l1   = off_dens + (size_t)2 * N * 4;                 // N f32
  const size_t off_ang  = off_l1 + (size_t)N * 4;                       // N f32

  float* sq = (float*)(ws + off_sq);
  unsigned short* hi = (unsigned short*)(ws + off_hi);
  unsigned* pk = (unsigned*)(ws + off_pk);
  float* dens = (float*)(ws + off_dens);
  float* l1p = (float*)(ws + off_l1);
  float* angp = (float*)(ws + off_ang);

  k_prep<<<(2 * N) / 4, 256, 0, stream>>>(emb, ref, hi, sq);
  k_knn1<<<dim3(N / 128, SPLITS, 2), 256, 0, stream>>>(hi, sq, pk);
  k_tail<<<N, 256, 0, stream>>>(emb, ref, sq, pk, dens, l1p, angp);
  k_final<<<1, 256, 0, stream>>>(l1p, dens, angp, out);
}

// Round 15
// 337.378 us; speedup vs baseline: 1.1514x; 1.0631x over previous
//
#include <hip/hip_runtime.h>

#define N 8192
#define D 512
#define KNN 15
#define SC 6       // per-scanner register list
#define NC 12      // per-split candidate list (2 scanners merged)
#define SPLITS 8
#define NCAND 24   // rescored candidates per row
#define NPAIR 105
#define EPSF 1e-8f

#define INF __int_as_float(0x7f800000)

typedef __attribute__((ext_vector_type(4))) float f32x4;
typedef __attribute__((ext_vector_type(4))) unsigned u32x4;
typedef __attribute__((ext_vector_type(8))) short s16x8;
typedef __attribute__((ext_vector_type(8))) unsigned short u16x8;
typedef unsigned long long u64;

typedef const unsigned int __attribute__((address_space(1)))* gp_t;
typedef unsigned int __attribute__((address_space(3)))* lp_t;

__device__ __forceinline__ void gl_lds16(const void* g, void* l) {
  __builtin_amdgcn_global_load_lds((gp_t)g, (lp_t)l, 16, 0, 0);
}

__device__ __forceinline__ unsigned short bf16_rne(float x) {
  unsigned int u = __float_as_uint(x);
  return (unsigned short)((u + 0x7fffu + ((u >> 16) & 1u)) >> 16);
}

#define VMCNT4 asm volatile("s_waitcnt vmcnt(4)" ::: "memory")
#define VMCNT0 asm volatile("s_waitcnt vmcnt(0)" ::: "memory")
#define LGKM0  asm volatile("s_waitcnt lgkmcnt(0)" ::: "memory")
#define CFENCE asm volatile("" ::: "memory")

// ---------------------------------------------------------------- fused sq-norms + bf16 cast (one input pass)
__global__ __launch_bounds__(256)
void k_prep(const float* __restrict__ A, const float* __restrict__ B,
            unsigned short* __restrict__ hi, float* __restrict__ sq)
{
  const int tid = threadIdx.x;
  const int lane = tid & 63;
  const int row = blockIdx.x * 4 + (tid >> 6);    // 0 .. 2N-1
  const float* src = (row < N) ? (A + (size_t)row * D)
                               : (B + (size_t)(row - N) * D);
  const float4* s4 = (const float4*)src + lane * 2;
  const float4 x0 = s4[0], x1 = s4[1];
  const float xs[8] = {x0.x, x0.y, x0.z, x0.w, x1.x, x1.y, x1.z, x1.w};
  u16x8 hv;
  float s = 0.f;
#pragma unroll
  for (int j = 0; j < 8; ++j) {
    hv[j] = bf16_rne(xs[j]);
    s = fmaf(xs[j], xs[j], s);
  }
  *(u16x8*)(hi + (size_t)row * D + lane * 8) = hv;
#pragma unroll
  for (int o = 32; o; o >>= 1) s += __shfl_xor(s, o);
  if (lane == 0) sq[row] = s;
}

// ================================================================ stage 1:
// approx (hi-only) MFMA gram + per-split top-12 candidate KEYS.
// key u32 = (f32bits(max(d2,0)) & ~8191) | global_col  (col < 8192, 13 bits).
// Scanner: BRANCHLESS sorted-insert network (identity when key >= tv[SC-1]).
__global__ __launch_bounds__(256, 4)
void k_knn1(const unsigned short* __restrict__ hi,
            const float* __restrict__ sqall,
            unsigned* __restrict__ pk)
{
  __shared__ __align__(16) char smem[40960];
  unsigned* DtU = (unsigned*)smem;          // [128][68] key tile
  unsigned* SK = (unsigned*)smem;           // [128][12] merge overlay

  const int tid = threadIdx.x;
  const int lane = tid & 63, w = tid >> 6;
  const int wr = w >> 1, wc = w & 1;
  const int fr = lane & 15, fq = lane >> 4;
  const int sgx = fq ^ ((fr >> 1) & 3);     // read-side seg swizzle

  const int rb = blockIdx.x, split = blockIdx.y, which = blockIdx.z;
  const int row0 = rb * 128;
  const int c0 = split * 1024;
  const unsigned short* Hi = hi + (size_t)which * N * D;
  const float* sq = sqall + which * N;

  const int rr = tid >> 2, sseg = tid & 3;
  const int ssg = sseg ^ ((rr >> 1) & 3);
  const unsigned short* pAh = Hi + (size_t)(row0 + rr) * D + ssg * 8;
  const unsigned short* pBh = Hi + (size_t)(c0 + rr) * D + ssg * 8;

  auto stage = [&](int sel) {
    char* d = smem + (sel << 14) + (w << 10);   // wave-uniform dest base
    gl_lds16(pAh, d);
    gl_lds16(pAh + 32768, d + 4096);            // rows +64 (+65536 B global)
    gl_lds16(pBh, d + 8192);
    gl_lds16(pBh + 32768, d + 12288);
    pAh += 32; pBh += 32;                        // next K-step
  };

  const int srow = tid >> 1, ssub = tid & 1;
  unsigned tv[SC];
#pragma unroll
  for (int j = 0; j < SC; ++j) tv[j] = 0xFFFFFFFFu;

  float sqr[4][4];
#pragma unroll
  for (int m = 0; m < 4; ++m)
#pragma unroll
    for (int j = 0; j < 4; ++j)
      sqr[m][j] = sq[row0 + wr * 64 + m * 16 + fq * 4 + j];

#pragma unroll 1
  for (int t = 0; t < 8; ++t) {
    const int ct = c0 + t * 128;
    float sqc[4];
#pragma unroll
    for (int n = 0; n < 4; ++n) sqc[n] = sq[ct + wc * 64 + n * 16 + fr];

    f32x4 acc[4][4];
#pragma unroll
    for (int m = 0; m < 4; ++m)
#pragma unroll
      for (int n = 0; n < 4; ++n) acc[m][n] = (f32x4){0.f, 0.f, 0.f, 0.f};

    stage(0);
    int cur = 0;
#pragma unroll 1
    for (int kt = 0; kt < 16; ++kt) {
      if (kt < 15) {
        stage(cur ^ 1);   // 8 outstanding
        VMCNT4;           // own 4 oldest = buf[cur] loads complete
      } else {
        VMCNT0;
      }
      __builtin_amdgcn_s_barrier();
      CFENCE;

      const short* Sb = (const short*)(smem + (cur << 14));
      s16x8 ah[4], bh[4];
#pragma unroll
      for (int m = 0; m < 4; ++m)
        ah[m] = *(const s16x8*)(Sb + (wr * 64 + m * 16 + fr) * 32 + sgx * 8);
#pragma unroll
      for (int n = 0; n < 4; ++n)
        bh[n] = *(const s16x8*)(Sb + 4096 + (wc * 64 + n * 16 + fr) * 32 + sgx * 8);
#pragma unroll
      for (int m = 0; m < 4; ++m)
#pragma unroll
        for (int n = 0; n < 4; ++n)
          acc[m][n] = __builtin_amdgcn_mfma_f32_16x16x32_bf16(ah[m], bh[n], acc[m][n], 0, 0, 0);

      LGKM0;
      __builtin_amdgcn_s_barrier();
      CFENCE;
      cur ^= 1;
    }
    pAh -= 512; pBh += 65024;

    // ---- epilogue: producer writes u32 KEYS; scanner = load + branchless insert
#pragma unroll 1
    for (int h = 0; h < 2; ++h) {
      if (wc == h) {
#pragma unroll
        for (int m = 0; m < 4; ++m)
#pragma unroll
          for (int n = 0; n < 4; ++n) {
            const int cl = n * 16 + fr;
            const int gcol = ct + h * 64 + cl;
            const int rbase = wr * 64 + m * 16 + fq * 4;
#pragma unroll
            for (int j = 0; j < 4; ++j) {
              const float d2 = fmaf(-2.0f, acc[m][n][j], sqr[m][j] + sqc[n]);
              unsigned key = (__float_as_uint(fmaxf(d2, 0.f)) & ~8191u) | (unsigned)gcol;
              if (row0 + rbase + j == gcol) key = 0xFFFFFFFFu;   // exclude self
              DtU[(rbase + j) * 68 + cl] = key;
            }
          }
      }
      __syncthreads();
      {
#pragma unroll 1
        for (int g = 0; g < 8; ++g) {
          const u32x4 dv = *(const u32x4*)&DtU[srow * 68 + ssub * 32 + g * 4];
#pragma unroll
          for (int i = 0; i < 4; ++i) {
            const unsigned key = dv[i];
            // branchless sorted-insert (descending j reads OLD tv[j-1]):
            // identity when key >= tv[SC-1]
#pragma unroll
            for (int j = SC - 1; j >= 1; --j)
              tv[j] = min(tv[j], max(tv[j - 1], key));
            tv[0] = min(tv[0], key);
          }
        }
      }
      __syncthreads();
    }
  }

  // ---- block end: merge 2 sorted scanner lists per row -> sorted top-12 keys
#pragma unroll
  for (int j = 0; j < SC; ++j) SK[srow * 12 + ssub * SC + j] = tv[j];
  __syncthreads();
  if (tid < 128) {
    const int grow = row0 + tid;
    const size_t pb = (((size_t)which * SPLITS + split) * N + grow) * NC;
    int p0 = 0, p1 = 0;
#pragma unroll
    for (int j = 0; j < NC; ++j) {
      const unsigned a = (p0 < SC) ? SK[tid * 12 + p0] : 0xFFFFFFFFu;
      const unsigned b = (p1 < SC) ? SK[tid * 12 + SC + p1] : 0xFFFFFFFFu;
      const bool ta = a <= b;
      pk[pb + j] = ta ? a : b;
      if (ta) ++p0; else ++p1;
    }
  }
}

// ================================================================ fused tail:
// per point i: rescore ref (wave 0) + cur (wave 1) via bitonic-128 candidate
// merge (96 real keys + pad) -> exact f32 top-15; in-LDS handoff;
// per-point stats; MFMA angular.
__global__ __launch_bounds__(256)
void k_tail(const float* __restrict__ emb, const float* __restrict__ ref,
            const float* __restrict__ sqall, const unsigned* __restrict__ pk,
            float* __restrict__ dens, float* __restrict__ l1p,
            float* __restrict__ angp)
{
  __shared__ __align__(16) short Vb[16][520];
  __shared__ float Gp[4][256];
  __shared__ float G[256];
  __shared__ float invn[16];
  __shared__ float cref[NPAIR];
  __shared__ float red2[256];
  __shared__ int idxs[2][16];      // [0]=ref neighbors, [1]=cur
  __shared__ float dls[2][16];

  const int i = blockIdx.x;
  const int tid = threadIdx.x;
  const int lane = tid & 63;
  const int w = tid >> 6;

  // ---- Phase A: waves 0 (ref, which=1) and 1 (cur, which=0) rescore
  if (w < 2) {
    const int which = 1 - w;
    const float* E = which ? ref : emb;
    const float* sqm = sqall + which * N;

    // load 96 candidate keys (8 splits x 12), pad to 128
    const int sp = lane >> 3, jj = lane & 7;
    const size_t kb = (((size_t)which * SPLITS + sp) * N + i) * NC;
    unsigned v0 = pk[kb + jj];
    unsigned v1 = (jj < NC - 8) ? pk[kb + 8 + jj] : 0xFFFFFFFFu;

    // bitonic sort 128 ascending; element g: g<64 -> v0[lane g], g>=64 -> v1[lane g-64]
#pragma unroll
    for (int k = 2; k <= 128; k <<= 1) {
#pragma unroll
      for (int s = k >> 1; s > 0; s >>= 1) {
        if (s == 64) {                       // only at k=128; pair (v0,v1), ascending
          const unsigned mn = min(v0, v1), mx = max(v0, v1);
          v0 = mn; v1 = mx;
        } else {
          const unsigned o0 = __shfl_xor(v0, s);
          const unsigned o1 = __shfl_xor(v1, s);
          const bool low = ((lane & s) == 0);
          const bool dir0 = ((lane & k) == 0);          // g = lane
          const bool dir1 = (((64 + lane) & k) == 0);   // g = 64+lane
          const unsigned a0 = min(v0, o0), b0 = max(v0, o0);
          v0 = (low == dir0) ? a0 : b0;
          const unsigned a1 = min(v1, o1), b1 = max(v1, o1);
          v1 = (low == dir1) ? a1 : b1;
        }
      }
    }
    // candidates = NCAND smallest = v0 of lanes 0..NCAND-1

    const float4* orow = (const float4*)(E + (size_t)i * D) + lane * 2;
    const float4 o0 = orow[0], o1 = orow[1];
    const float sqr_ = sqm[i];

    u64 mykey = ~0ull;
#pragma unroll 4
    for (int c = 0; c < NCAND; ++c) {
      const int cl = (int)(__shfl(v0, c) & 8191u);
      const float4* crow = (const float4*)(E + (size_t)cl * D) + lane * 2;
      const float4 c0 = crow[0], c1 = crow[1];
      float s = o0.x*c0.x + o0.y*c0.y + o0.z*c0.z + o0.w*c0.w
              + o1.x*c1.x + o1.y*c1.y + o1.z*c1.z + o1.w*c1.w;
#pragma unroll
      for (int o = 32; o; o >>= 1) s += __shfl_xor(s, o);
      float d2 = fmaf(-2.0f, s, sqr_ + sqm[cl]);
      d2 = fmaxf(d2, 0.0f);
      const u64 key = ((u64)__float_as_uint(d2) << 32) | (unsigned)cl;
      if (lane == c) mykey = key;
    }

    // bitonic sort ascending across 64 lanes (lanes >= NCAND hold ~0ull)
#pragma unroll
    for (int k = 2; k <= 64; k <<= 1) {
#pragma unroll
      for (int j = k >> 1; j > 0; j >>= 1) {
        const u64 o = __shfl_xor(mykey, j);
        const bool up = ((lane & k) == 0);
        const bool lower = ((lane & j) == 0);
        const u64 mn = (mykey < o) ? mykey : o;
        const u64 mx = (mykey < o) ? o : mykey;
        mykey = (lower == up) ? mn : mx;
      }
    }

    if (lane < KNN) {
      const float d2v = __uint_as_float((unsigned)(mykey >> 32));
      dls[w][lane] = (d2v > 0.f) ? sqrtf(fmaxf(d2v, 1e-24f)) : 0.f;
      idxs[w][lane] = (int)(mykey & 0xffffffffu);
    }
  }
  __syncthreads();

  // ---- Phase A2: per-point stats (dls[0]=ref, dls[1]=cur)
  if (tid == 0) {
    float mr = 0.f, mc = 0.f;
#pragma unroll
    for (int j = 0; j < KNN; ++j) { mr += dls[0][j]; mc += dls[1][j]; }
    mr *= (1.0f / KNN); mc *= (1.0f / KNN);
    const float ir = 1.0f / (mr + EPSF);
    const float ic = 1.0f / (mc + EPSF);
    float s1 = 0.f;
#pragma unroll
    for (int j = 0; j < KNN; ++j) {
      const float t = dls[1][j] * ic - dls[0][j] * ir;
      s1 = fmaf(t, t, s1);
    }
    dens[i] = ic;
    dens[N + i] = ir;
    l1p[i] = s1;
  }
  __syncthreads();

  // ---- Phase B: angular via per-point MFMA gram (pass 0 = ref, 1 = cur)
  const int base = lane * 8;
  float acc = 0.f;

#pragma unroll 1
  for (int pass = 0; pass < 2; ++pass) {
    const float* E = pass ? emb : ref;

    const float4* er = (const float4*)(E + (size_t)i * D) + lane * 2;
    const float4 e0 = er[0], e1 = er[1];

#pragma unroll 1
    for (int j = w; j < 16; j += 4) {
      u16x8 hv;
      if (j < 15) {
        const float* src = E + (size_t)idxs[pass][j] * D;
        const float4 x0 = *(const float4*)(src + base);
        const float4 x1 = *(const float4*)(src + base + 4);
        const float dd[8] = {x0.x-e0.x, x0.y-e0.y, x0.z-e0.z, x0.w-e0.w,
                             x1.x-e1.x, x1.y-e1.y, x1.z-e1.z, x1.w-e1.w};
#pragma unroll
        for (int q = 0; q < 8; ++q) hv[q] = bf16_rne(dd[q]);
      } else {
#pragma unroll
        for (int q = 0; q < 8; ++q) hv[q] = 0;
      }
      *(u16x8*)&Vb[j][base] = hv;
    }
    __syncthreads();

    {
      const int r = lane & 15, fq = lane >> 4;
      f32x4 g = (f32x4){0.f, 0.f, 0.f, 0.f};
#pragma unroll
      for (int s = 0; s < 4; ++s) {
        const s16x8 f = *(const s16x8*)&Vb[r][w * 128 + s * 32 + fq * 8];
        g = __builtin_amdgcn_mfma_f32_16x16x32_bf16(f, f, g, 0, 0, 0);
      }
#pragma unroll
      for (int r2 = 0; r2 < 4; ++r2)
        Gp[w][(fq * 4 + r2) * 16 + r] = g[r2];
    }
    __syncthreads();

    G[tid] = Gp[0][tid] + Gp[1][tid] + Gp[2][tid] + Gp[3][tid];
    __syncthreads();
    if (tid < 16) invn[tid] = 1.0f / fmaxf(sqrtf(G[tid * 17]), 1e-12f);
    __syncthreads();

    if (tid < NPAIR) {
      int a = 0, q = tid, rem = KNN - 1;
      while (q >= rem) { q -= rem; ++a; --rem; }
      const int b = a + 1 + q;
      const float cosv = G[a * 16 + b] * invn[a] * invn[b];
      if (pass == 0) cref[tid] = cosv;
      else { const float dd = cosv - cref[tid]; acc = dd * dd; }
    }
    __syncthreads();
  }

  red2[tid] = acc;
  __syncthreads();
  for (int o = 128; o; o >>= 1) {
    if (tid < o) red2[tid] += red2[tid + o];
    __syncthreads();
  }
  if (tid == 0) angp[i] = red2[0];
}

// ---------------------------------------------------------------- final combine
__global__ __launch_bounds__(256)
void k_final(const float* __restrict__ l1p, const float* __restrict__ dens,
             const float* __restrict__ angp, float* __restrict__ out)
{
  __shared__ float red[256];
  const int t = threadIdx.x;

  float sc = 0.f, sr = 0.f;
  for (int n = t; n < N; n += 256) { sc += dens[n]; sr += dens[N + n]; }
  red[t] = sc; __syncthreads();
  for (int o = 128; o; o >>= 1) { if (t < o) red[t] += red[t + o]; __syncthreads(); }
  float scm = red[0]; __syncthreads();
  red[t] = sr; __syncthreads();
  for (int o = 128; o; o >>= 1) { if (t < o) red[t] += red[t + o]; __syncthreads(); }
  float srm = red[0]; __syncthreads();

  const float icm = 1.0f / (scm / (float)N + EPSF);
  const float irm = 1.0f / (srm / (float)N + EPSF);

  float l2 = 0.f;
  for (int n = t; n < N; n += 256) {
    const float dd = dens[n] * icm - dens[N + n] * irm;
    l2 = fmaf(dd, dd, l2);
  }
  red[t] = l2; __syncthreads();
  for (int o = 128; o; o >>= 1) { if (t < o) red[t] += red[t + o]; __syncthreads(); }
  const float l2sum = red[0]; __syncthreads();

  float l1 = 0.f;
  for (int n = t; n < N; n += 256) l1 += l1p[n];
  red[t] = l1; __syncthreads();
  for (int o = 128; o; o >>= 1) { if (t < o) red[t] += red[t + o]; __syncthreads(); }
  const float l1sum = red[0]; __syncthreads();

  float l3 = 0.f;
  for (int n = t; n < N; n += 256) l3 += angp[n];
  red[t] = l3; __syncthreads();
  for (int o = 128; o; o >>= 1) { if (t < o) red[t] += red[t + o]; __syncthreads(); }
  const float l3sum = red[0];

  if (t == 0) {
    out[0] = l1sum / (float)(N * KNN)
           + 0.5f * l2sum / (float)N
           + 0.5f * l3sum / (float)(N * NPAIR);
  }
}

// ---------------------------------------------------------------- launch
extern "C" void kernel_launch(void* const* d_in, const int* in_sizes, int n_in,
                              void* d_out, int out_size, void* d_ws, size_t ws_size,
                              hipStream_t stream)
{
  const float* emb = (const float*)d_in[0];
  const float* ref = (const float*)d_in[1];
  float* out = (float*)d_out;
  char* ws = (char*)d_ws;

  const size_t off_sq   = 0;                                            // 2N f32
  const size_t off_hi   = off_sq + (size_t)2 * N * 4;                   // 2ND bf16
  const size_t off_pk   = off_hi + (size_t)2 * N * D * 2;               // 2*8*N*12 u32
  const size_t off_dens = off_pk + (size_t)2 * SPLITS * N * NC * 4;     // 2N f32
  const size_t off_l1   = off_dens + (size_t)2 * N * 4;                 // N f32
  const size_t off_ang  = off_l1 + (size_t)N * 4;                       // N f32

  float* sq = (float*)(ws + off_sq);
  unsigned short* hi = (unsigned short*)(ws + off_hi);
  unsigned* pk = (unsigned*)(ws + off_pk);
  float* dens = (float*)(ws + off_dens);
  float* l1p = (float*)(ws + off_l1);
  float* angp = (float*)(ws + off_ang);

  k_prep<<<(2 * N) / 4, 256, 0, stream>>>(emb, ref, hi, sq);
  k_knn1<<<dim3(N / 128, SPLITS, 2), 256, 0, stream>>>(hi, sq, pk);
  k_tail<<<N, 256, 0, stream>>>(emb, ref, sq, pk, dens, l1p, angp);
  k_final<<<1, 256, 0, stream>>>(l1p, dens, angp, out);
}